// Round 11
// baseline (211.691 us; speedup 1.0000x reference)
//
#include <hip/hip_runtime.h>

#define CH 512
#define HEADS 4
#define HD 128
#define NPIX 1024
#define BATCH 16
#define GROUPS 32
#define GSZ 16
#define EPS 1e-5f

typedef _Float16 f16;
typedef _Float16 f16x8 __attribute__((ext_vector_type(8)));
typedef _Float16 f16x4 __attribute__((ext_vector_type(4)));
typedef float f32x4 __attribute__((ext_vector_type(4)));

__device__ __forceinline__ void gld16(const f16* g, f16* l) {
    __builtin_amdgcn_global_load_lds((__attribute__((address_space(1))) const void*)g,
                                     (__attribute__((address_space(3))) void*)l, 16, 0, 0);
}

// ---------------- K1: fused [groupnorm+transpose | weight-convert] ----------------
// blocks 0..511: groupnorm (one per (g,b)); blocks 512..895: weight pre-transpose.
__global__ __launch_bounds__(256, 2) void k_pre(const float* __restrict__ x, const float* __restrict__ gamma,
                                                const float* __restrict__ beta, f16* __restrict__ xnT,
                                                const float* __restrict__ wq, const float* __restrict__ wp,
                                                f16* __restrict__ wqT, f16* __restrict__ wpT) {
    __shared__ float xs[GSZ * NPIX];   // 64 KB
    __shared__ float red[8];
    __shared__ float stat2[2];
    int bidx = blockIdx.x;
    if (bidx >= 512) {
        // ---- weight convert branch ----
        int c = (bidx - 512) * 256 + threadIdx.x;
        {
            int ot = c >> 13, kbl = (c >> 7) & 63, ol = c & 127;
            const float* s = wq + ((size_t)(ot * 128 + ol)) * CH + kbl * 8;
            f32x4 a = *(const f32x4*)s, b2 = *(const f32x4*)(s + 4);
            f16x8 v;
            v[0] = (f16)a.x; v[1] = (f16)a.y; v[2] = (f16)a.z; v[3] = (f16)a.w;
            v[4] = (f16)b2.x; v[5] = (f16)b2.y; v[6] = (f16)b2.z; v[7] = (f16)b2.w;
            *(f16x8*)(wqT + (size_t)c * 8) = v;
        }
        if (c < 32768) {
            int ot = c >> 13, kbl = (c >> 7) & 63, ol = c & 127;
            const float* s = wp + ((size_t)(ot * 128 + ol)) * CH + kbl * 8;
            f32x4 a = *(const f32x4*)s, b2 = *(const f32x4*)(s + 4);
            f16x8 v;
            v[0] = (f16)a.x; v[1] = (f16)a.y; v[2] = (f16)a.z; v[3] = (f16)a.w;
            v[4] = (f16)b2.x; v[5] = (f16)b2.y; v[6] = (f16)b2.z; v[7] = (f16)b2.w;
            *(f16x8*)(wpT + (size_t)c * 8) = v;
        }
        return;
    }
    // ---- groupnorm branch ----
    int g = bidx & 31, b = bidx >> 5;
    const f32x4* x4 = (const f32x4*)(x + ((size_t)(b * GROUPS + g)) * (GSZ * NPIX));
    float s = 0.f, ss = 0.f;
    for (int i = threadIdx.x; i < GSZ * NPIX / 4; i += 256) {
        f32x4 v = x4[i];
        *(f32x4*)&xs[i * 4] = v;
        s  += v.x + v.y + v.z + v.w;
        ss += v.x * v.x + v.y * v.y + v.z * v.z + v.w * v.w;
    }
    for (int off = 32; off; off >>= 1) { s += __shfl_down(s, off); ss += __shfl_down(ss, off); }
    int wv = threadIdx.x >> 6, ln = threadIdx.x & 63;
    if (ln == 0) { red[wv] = s; red[4 + wv] = ss; }
    __syncthreads();
    if (threadIdx.x == 0) {
        float S = red[0] + red[1] + red[2] + red[3];
        float SS = red[4] + red[5] + red[6] + red[7];
        float mu = S / (GSZ * NPIX);
        float var = SS / (GSZ * NPIX) - mu * mu;
        stat2[0] = mu; stat2[1] = rsqrtf(var + EPS);
    }
    __syncthreads();
    float mu = stat2[0], rstd = stat2[1];
    int ch = threadIdx.x >> 7;
    int n  = threadIdx.x & 127;
    float gl[8], bl[8];
#pragma unroll
    for (int i = 0; i < 8; i++) {
        float gv = gamma[g * 16 + ch * 8 + i] * rstd;
        gl[i] = gv;
        bl[i] = beta[g * 16 + ch * 8 + i] - mu * gv;
    }
    f16* tb0 = xnT + ((size_t)(b * 8)) * 65536 + (g * 2 + ch) * 1024 + n * 8;
#pragma unroll
    for (int nt = 0; nt < 8; nt++) {
        f16x8 o;
#pragma unroll
        for (int i = 0; i < 8; i++)
            o[i] = (f16)(xs[(ch * 8 + i) * 1024 + nt * 128 + n] * gl[i] + bl[i]);
        *(f16x8*)(tb0 + (size_t)nt * 65536) = o;
    }
}

// ---------------- K2: QKV GEMM v2 — 128M x 256N block tile, BK=64 ----------------
// One block covers 2 nt-tiles: wT staged once per 256 pixels; 64 MFMA per
// barrier-pair per wave (2x v1). LDS: staging 48 KB (union w/ 32 KB Cf).
__global__ __launch_bounds__(256, 2) void k_qkv(const f16* __restrict__ wT, const float* __restrict__ bias,
                                                const f16* __restrict__ xnT, f16* __restrict__ qF,
                                                f16* __restrict__ kTl, f16* __restrict__ vTl) {
    int ntp = blockIdx.x, ot = blockIdx.y, b = blockIdx.z;
    int o0 = ot * 128;
    __shared__ union SM {
        struct { f16 As[8192]; f16 Bs[16384]; } s;   // As [kbl8][128][8], Bs [kbl8][256][8]
        f16 Cf[16384];
    } sm;
    __shared__ float biasS[128];
    if (threadIdx.x < 128) biasS[threadIdx.x] = bias[o0 + threadIdx.x];
    int tid = threadIdx.x, lane = tid & 63, wv = tid >> 6;
    int wr = wv >> 1, wc = wv & 1;      // wave tile: 64 M-rows x 128 N-cols
    int l15 = lane & 15, quad = lane >> 4;
    const f16* wA = wT + (size_t)ot * 65536;
    const f16* xB0 = xnT + ((size_t)(b * 8 + ntp * 2)) * 65536;
    const f16* xB1 = xnT + ((size_t)(b * 8 + ntp * 2 + 1)) * 65536;
    f32x4 acc[4][8] = {};
    for (int kk = 0; kk < CH; kk += 64) {
        __syncthreads();
        const f16* sa = wA + (size_t)(kk >> 3) * 1024;
#pragma unroll
        for (int i = 0; i < 12; i++) {
            int sid = wv * 12 + i;       // 0..47
            if (sid < 16) {
                gld16(sa + (size_t)(sid * 64 + lane) * 8, sm.s.As + sid * 512);
            } else {
                int t = sid - 16;        // 0..31
                int kbl = t >> 2, half = (t >> 1) & 1, sub = t & 1;
                const f16* src = (half ? xB1 : xB0) + (size_t)((kk >> 3) + kbl) * 1024 + (size_t)(sub * 64 + lane) * 8;
                gld16(src, sm.s.Bs + kbl * 2048 + half * 1024 + sub * 512);
            }
        }
        __syncthreads();
#pragma unroll
        for (int dk = 0; dk < 2; dk++) {
            f16x8 af[4], bf[8];
#pragma unroll
            for (int t = 0; t < 4; t++)
                af[t] = *(const f16x8*)(sm.s.As + (dk * 4 + quad) * 1024 + (wr * 64 + t * 16 + l15) * 8);
#pragma unroll
            for (int t = 0; t < 8; t++)
                bf[t] = *(const f16x8*)(sm.s.Bs + (dk * 4 + quad) * 2048 + (wc * 128 + t * 16 + l15) * 8);
#pragma unroll
            for (int tm = 0; tm < 4; tm++)
#pragma unroll
                for (int tn = 0; tn < 8; tn++)
                    acc[tm][tn] = __builtin_amdgcn_mfma_f32_16x16x32_f16(af[tm], bf[tn], acc[tm][tn], 0, 0, 0);
        }
    }
    int which = ot >> 2, h = ot & 3;
    // two-pass epilogue: one nt tile per pass
#pragma unroll
    for (int half = 0; half < 2; half++) {
        __syncthreads();   // staging reads done / prev-pass stores done
        if (wc == half) {
#pragma unroll
            for (int tm = 0; tm < 4; tm++)
#pragma unroll
                for (int tn = 0; tn < 8; tn++) {
                    int ob = wr * 64 + tm * 16 + quad * 4;
                    int n  = tn * 16 + l15;           // local n within the 128-tile
                    f16x4 pv;
#pragma unroll
                    for (int r = 0; r < 4; r++) pv[r] = (f16)(acc[tm][tn][r] + biasS[ob + r]);
                    if (which == 0) {
                        int addr = ((((n >> 5) * 2 + ((n >> 4) & 1)) * 4 + (ob >> 5)) * 512)
                                 + ((ob >> 3) & 3) * 128 + (n & 15) * 8 + (quad & 1) * 4;
                        *(f16x4*)&sm.Cf[addr] = pv;
                    } else if (which == 1) {
                        int addr = (ob >> 3) * 1024 + n * 8 + (quad & 1) * 4;
                        *(f16x4*)&sm.Cf[addr] = pv;
                    } else {
#pragma unroll
                        for (int r = 0; r < 4; r++)
                            sm.Cf[(n >> 3) * 1024 + (ob + r) * 8 + (n & 7)] = pv[r];
                    }
                }
        }
        __syncthreads();
        int nt = ntp * 2 + half;
        f16* tb = (which == 0) ? (qF + ((size_t)((b * 4 + h) * 8 + nt)) * 16384)
                : (which == 1) ? (kTl + ((size_t)((b * 4 + h) * 8 + nt)) * 16384)
                               : (vTl + ((size_t)((b * 4 + h) * 8 + nt)) * 16384);
#pragma unroll
        for (int i = 0; i < 8; i++) {
            int cid = tid + i * 256;
            *(f16x8*)(tb + (size_t)cid * 8) = *(const f16x8*)(sm.Cf + cid * 8);
        }
    }
}

// ---------------- K3: flash attention v6.1 (exact R7-measured version, FROZEN) ----------------
// __expf softmax, prefetch after P-store — this exact instruction mix measured
// 55 us / WRITE 22.5 MB; exp2f variants (R8/R9) triggered scheduler-induced spill.
__global__ __launch_bounds__(512, 1) void k_attn(const f16* __restrict__ qF, const f16* __restrict__ kTl,
                                                 const f16* __restrict__ vTl, f16* __restrict__ oT) {
    int bid = blockIdx.x;
    int ntp = bid >> 6, group = bid & 63;
    int b = group >> 2, h = group & 3;
    extern __shared__ f16 smem[];
    f16* Kl = smem;
    f16* Vl = smem + 16384;
    f16* PA = smem + 32768;
    f16* PB = smem + 49152;
    int tid = threadIdx.x, lane = tid & 63, wv = tid >> 6;
    int wq = wv & 3;
    int tile = wv >> 2;
    int nt = ntp * 2 + tile;
    int l15 = lane & 15, quad = lane >> 4;
    const f16* qb = qF + ((size_t)(group * 8 + nt)) * 16384;
    const f16* kb = kTl + (size_t)group * 8 * 16384;
    const f16* vb = vTl + (size_t)group * 8 * 16384;
    f16* Preg = tile ? PB : PA;

    f16x8 aq[2][4];
#pragma unroll
    for (int t = 0; t < 2; t++)
#pragma unroll
        for (int dk = 0; dk < 4; dk++) {
            int seg = (wq * 2 + t) * 4 + dk;
            f16x8 v = *(const f16x8*)(qb + seg * 512 + lane * 8);
            aq[t][dk] = v * (f16)0.08838834764831845f;
        }

    float m_i[2] = {-1e30f, -1e30f}, l_i[2] = {0.f, 0.f};
    f32x4 oaccT[2][8] = {};

    const f16* sbase = tile ? vb : kb;
    f16* dstL = tile ? Vl : Kl;
    f16x8 buf[8];
#pragma unroll
    for (int i = 0; i < 8; i++)
        buf[i] = *(const f16x8*)(sbase + (size_t)((wq * 8 + i) * 64 + lane) * 8);

    for (int mc = 0; mc < 8; mc++) {
        __syncthreads();
#pragma unroll
        for (int i = 0; i < 8; i++)
            *(f16x8*)&dstL[(wq * 8 + i) * 512 + lane * 8] = buf[i];
        __syncthreads();

        // S^T = K Q^T
        f32x4 st[2][8] = {};
#pragma unroll
        for (int dk = 0; dk < 4; dk++) {
            f16x8 kf[8];
#pragma unroll
            for (int t = 0; t < 8; t++)
                kf[t] = *(const f16x8*)&Kl[(dk * 4 + quad) * 1024 + (t * 16 + l15) * 8];
#pragma unroll
            for (int tr = 0; tr < 2; tr++)
#pragma unroll
                for (int tc = 0; tc < 8; tc++)
                    st[tr][tc] = __builtin_amdgcn_mfma_f32_16x16x32_f16(kf[tc], aq[tr][dk], st[tr][tc], 0, 0, 0);
        }

        // online softmax: pairwise-tree in-lane reductions + 2 shuffles
#pragma unroll
        for (int tr = 0; tr < 2; tr++) {
            float a[8];
#pragma unroll
            for (int tc = 0; tc < 8; tc++)
                a[tc] = fmaxf(fmaxf(st[tr][tc][0], st[tr][tc][1]), fmaxf(st[tr][tc][2], st[tr][tc][3]));
#pragma unroll
            for (int s = 4; s; s >>= 1)
#pragma unroll
                for (int k = 0; k < 4; k++) if (k < s) a[k] = fmaxf(a[k], a[k + s]);
            float mx = a[0];
            mx = fmaxf(mx, __shfl_xor(mx, 16));
            mx = fmaxf(mx, __shfl_xor(mx, 32));
            float mnew = fmaxf(m_i[tr], mx);
            float alpha = __expf(m_i[tr] - mnew);
            m_i[tr] = mnew;
            float r4[8];
#pragma unroll
            for (int tc = 0; tc < 8; tc++) {
                float p0 = __expf(st[tr][tc][0] - mnew);
                float p1 = __expf(st[tr][tc][1] - mnew);
                float p2 = __expf(st[tr][tc][2] - mnew);
                float p3 = __expf(st[tr][tc][3] - mnew);
                st[tr][tc][0] = p0; st[tr][tc][1] = p1;
                st[tr][tc][2] = p2; st[tr][tc][3] = p3;
                r4[tc] = (p0 + p1) + (p2 + p3);
            }
#pragma unroll
            for (int s = 4; s; s >>= 1)
#pragma unroll
                for (int k = 0; k < 4; k++) if (k < s) r4[k] += r4[k + s];
            float rs = r4[0];
            rs += __shfl_xor(rs, 16);
            rs += __shfl_xor(rs, 32);
            l_i[tr] = l_i[tr] * alpha + rs;
#pragma unroll
            for (int tc = 0; tc < 8; tc++) {
                oaccT[tr][tc].x *= alpha; oaccT[tr][tc].y *= alpha;
                oaccT[tr][tc].z *= alpha; oaccT[tr][tc].w *= alpha;
            }
        }

        // P store (wave-private rows)
#pragma unroll
        for (int tr = 0; tr < 2; tr++) {
            int n = wq * 32 + tr * 16 + l15;
#pragma unroll
            for (int tc = 0; tc < 8; tc++) {
                int blk = tc * 2 + (quad >> 1);
                f16x4 pv;
#pragma unroll
                for (int r = 0; r < 4; r++) pv[r] = (f16)st[tr][tc][r];
                *(f16x4*)&Preg[n * 128 + ((blk ^ (n & 15)) << 3) + ((quad & 1) << 2)] = pv;
            }
        }

        // prefetch next K or V tile
        if (mc < 7) {
            const f16* s = sbase + (size_t)(mc + 1) * 16384;
#pragma unroll
            for (int i = 0; i < 8; i++)
                buf[i] = *(const f16x8*)(s + (size_t)((wq * 8 + i) * 64 + lane) * 8);
        }

        // O^T += V^T P
#pragma unroll
        for (int mk = 0; mk < 4; mk++) {
            f16x8 vf[8], pf[2];
#pragma unroll
            for (int t = 0; t < 8; t++)
                vf[t] = *(const f16x8*)&Vl[(mk * 4 + quad) * 1024 + (t * 16 + l15) * 8];
#pragma unroll
            for (int tr = 0; tr < 2; tr++) {
                int n = wq * 32 + tr * 16 + l15;
                int blk = mk * 4 + quad;
                pf[tr] = *(const f16x8*)&Preg[n * 128 + ((blk ^ (n & 15)) << 3)];
            }
#pragma unroll
            for (int tr = 0; tr < 2; tr++)
#pragma unroll
                for (int tc = 0; tc < 8; tc++)
                    oaccT[tr][tc] = __builtin_amdgcn_mfma_f32_16x16x32_f16(vf[tc], pf[tr], oaccT[tr][tc], 0, 0, 0);
        }
    }

    // epilogue: O -> own P region, then block-coalesced f16x8 stores
#pragma unroll
    for (int tr = 0; tr < 2; tr++) {
        float inv = 1.f / l_i[tr];
        int n = wq * 32 + tr * 16 + l15;
#pragma unroll
        for (int tc = 0; tc < 8; tc++) {
            int blk = tc * 2 + (quad >> 1);
            f16x4 ov;
#pragma unroll
            for (int r = 0; r < 4; r++) ov[r] = (f16)(oaccT[tr][tc][r] * inv);
            *(f16x4*)&Preg[n * 128 + ((blk ^ (n & 15)) << 3) + ((quad & 1) << 2)] = ov;
        }
    }
    __syncthreads();
    f16* ob = oT + ((size_t)(b * 8 + nt)) * 65536;
    int t256 = tid & 255;
#pragma unroll
    for (int i = 0; i < 8; i++) {
        int cid = t256 + i * 256;
        int cbl = cid >> 7, n = cid & 127;
        f16x8 v = *(const f16x8*)&Preg[n * 128 + ((cbl ^ (n & 15)) << 3)];
        *(f16x8*)(ob + (size_t)(h * 16 + cbl) * 1024 + n * 8) = v;
    }
}

// ---------------- K4: proj GEMM + bias + residual -> fp32 out ----------------
__global__ __launch_bounds__(256, 3) void k_proj(const f16* __restrict__ wT, const float* __restrict__ bias,
                                                 const f16* __restrict__ oT, const float* __restrict__ x,
                                                 float* __restrict__ out) {
    int nt = blockIdx.x, ot = blockIdx.y, b = blockIdx.z;
    int n0 = nt * 128, o0 = ot * 128;
    __shared__ union SM {
        struct { f16 As[8192]; f16 Bs[8192]; } s;
        f16 Cs[128][136];
    } sm;
    __shared__ float biasS[128];
    if (threadIdx.x < 128) biasS[threadIdx.x] = bias[o0 + threadIdx.x];
    int tid = threadIdx.x, lane = tid & 63, wv = tid >> 6;
    int wr = wv >> 1, wc = wv & 1;
    int l15 = lane & 15, quad = lane >> 4;
    const f16* wA = wT + (size_t)ot * 65536;
    const f16* xB = oT + ((size_t)(b * 8 + nt)) * 65536;
    f32x4 acc[4][4] = {};
    for (int kk = 0; kk < CH; kk += 64) {
        __syncthreads();
        const f16* sa = wA + (size_t)(kk >> 3) * 1024;
        const f16* sb = xB + (size_t)(kk >> 3) * 1024;
#pragma unroll
        for (int i = 0; i < 4; i++) {
            int s = wv * 4 + i;
            gld16(sa + (size_t)(s * 64 + lane) * 8, sm.s.As + s * 512);
            gld16(sb + (size_t)(s * 64 + lane) * 8, sm.s.Bs + s * 512);
        }
        __syncthreads();
#pragma unroll
        for (int dk = 0; dk < 2; dk++) {
            f16x8 af[4], bf[4];
#pragma unroll
            for (int t = 0; t < 4; t++) {
                af[t] = *(const f16x8*)(sm.s.As + (dk * 4 + quad) * 1024 + (wr * 64 + t * 16 + l15) * 8);
                bf[t] = *(const f16x8*)(sm.s.Bs + (dk * 4 + quad) * 1024 + (wc * 64 + t * 16 + l15) * 8);
            }
#pragma unroll
            for (int tm = 0; tm < 4; tm++)
#pragma unroll
                for (int tn = 0; tn < 4; tn++)
                    acc[tm][tn] = __builtin_amdgcn_mfma_f32_16x16x32_f16(af[tm], bf[tn], acc[tm][tn], 0, 0, 0);
        }
    }
    __syncthreads();
#pragma unroll
    for (int tm = 0; tm < 4; tm++)
#pragma unroll
        for (int tn = 0; tn < 4; tn++)
#pragma unroll
            for (int r = 0; r < 4; r++) {
                int o = wr * 64 + tm * 16 + quad * 4 + r;
                int n = wc * 64 + tn * 16 + l15;
                sm.Cs[o][n] = (f16)(acc[tm][tn][r] + biasS[o]);
            }
    __syncthreads();
#pragma unroll
    for (int i = 0; i < 8; i++) {
        int cid = tid + i * 256;
        int row = cid >> 4, off = (cid & 15) * 8;
        f16x8 v = *(const f16x8*)&sm.Cs[row][off];
        size_t gofs = ((size_t)(b * CH) + o0 + row) * NPIX + n0 + off;
        const float* xp = x + gofs;
        float* op = out + gofs;
        f32x4 o0v, o1v;
        o0v.x = xp[0] + (float)v[0]; o0v.y = xp[1] + (float)v[1];
        o0v.z = xp[2] + (float)v[2]; o0v.w = xp[3] + (float)v[3];
        o1v.x = xp[4] + (float)v[4]; o1v.y = xp[5] + (float)v[5];
        o1v.z = xp[6] + (float)v[6]; o1v.w = xp[7] + (float)v[7];
        *(f32x4*)op = o0v; *(f32x4*)(op + 4) = o1v;
    }
}

extern "C" void kernel_launch(void* const* d_in, const int* in_sizes, int n_in,
                              void* d_out, int out_size, void* d_ws, size_t ws_size,
                              hipStream_t stream) {
    const float* x     = (const float*)d_in[0];
    const float* gamma = (const float*)d_in[1];
    const float* beta  = (const float*)d_in[2];
    const float* wqkv  = (const float*)d_in[3];
    const float* bqkv  = (const float*)d_in[4];
    const float* wproj = (const float*)d_in[5];
    const float* bproj = (const float*)d_in[6];
    float* out = (float*)d_out;

    char* p = (char*)d_ws;
    f16* wqT = (f16*)p;           p += (size_t)3 * CH * CH * 2;
    f16* wpT = (f16*)p;           p += (size_t)CH * CH * 2;
    f16* xnT = (f16*)p;           p += (size_t)BATCH * NPIX * CH * 2;
    f16* qF  = (f16*)p;           p += (size_t)BATCH * HEADS * NPIX * HD * 2;
    f16* kTl = (f16*)p;           p += (size_t)BATCH * HEADS * NPIX * HD * 2;
    f16* vTl = (f16*)p;           p += (size_t)BATCH * HEADS * NPIX * HD * 2;
    f16* oT  = (f16*)p;           p += (size_t)BATCH * NPIX * CH * 2;

    k_pre<<<dim3(896), 256, 0, stream>>>(x, gamma, beta, xnT, wqkv, wproj, wqT, wpT);
    k_qkv<<<dim3(4, 12, BATCH), 256, 0, stream>>>(wqT, bqkv, xnT, qF, kTl, vTl);

    hipFuncSetAttribute((const void*)k_attn, hipFuncAttributeMaxDynamicSharedMemorySize, 131072);
    k_attn<<<dim3(256), 512, 131072, stream>>>(qF, kTl, vTl, oT);

    k_proj<<<dim3(8, 4, BATCH), 256, 0, stream>>>(wpT, bproj, oT, x, out);
}

// Round 12
// 199.787 us; speedup vs baseline: 1.0596x; 1.0596x over previous
//
#include <hip/hip_runtime.h>

#define CH 512
#define HEADS 4
#define HD 128
#define NPIX 1024
#define BATCH 16
#define GROUPS 32
#define GSZ 16
#define EPS 1e-5f

typedef _Float16 f16;
typedef _Float16 f16x8 __attribute__((ext_vector_type(8)));
typedef _Float16 f16x4 __attribute__((ext_vector_type(4)));
typedef float f32x4 __attribute__((ext_vector_type(4)));

__device__ __forceinline__ void gld16(const f16* g, f16* l) {
    __builtin_amdgcn_global_load_lds((__attribute__((address_space(1))) const void*)g,
                                     (__attribute__((address_space(3))) void*)l, 16, 0, 0);
}

// ---------------- K1: fused [groupnorm+transpose | weight-convert] ----------------
// blocks 0..511: groupnorm (one per (g,b)); blocks 512..895: weight pre-transpose.
__global__ __launch_bounds__(256, 2) void k_pre(const float* __restrict__ x, const float* __restrict__ gamma,
                                                const float* __restrict__ beta, f16* __restrict__ xnT,
                                                const float* __restrict__ wq, const float* __restrict__ wp,
                                                f16* __restrict__ wqT, f16* __restrict__ wpT) {
    __shared__ float xs[GSZ * NPIX];   // 64 KB
    __shared__ float red[8];
    __shared__ float stat2[2];
    int bidx = blockIdx.x;
    if (bidx >= 512) {
        // ---- weight convert branch ----
        int c = (bidx - 512) * 256 + threadIdx.x;
        {
            int ot = c >> 13, kbl = (c >> 7) & 63, ol = c & 127;
            const float* s = wq + ((size_t)(ot * 128 + ol)) * CH + kbl * 8;
            f32x4 a = *(const f32x4*)s, b2 = *(const f32x4*)(s + 4);
            f16x8 v;
            v[0] = (f16)a.x; v[1] = (f16)a.y; v[2] = (f16)a.z; v[3] = (f16)a.w;
            v[4] = (f16)b2.x; v[5] = (f16)b2.y; v[6] = (f16)b2.z; v[7] = (f16)b2.w;
            *(f16x8*)(wqT + (size_t)c * 8) = v;
        }
        if (c < 32768) {
            int ot = c >> 13, kbl = (c >> 7) & 63, ol = c & 127;
            const float* s = wp + ((size_t)(ot * 128 + ol)) * CH + kbl * 8;
            f32x4 a = *(const f32x4*)s, b2 = *(const f32x4*)(s + 4);
            f16x8 v;
            v[0] = (f16)a.x; v[1] = (f16)a.y; v[2] = (f16)a.z; v[3] = (f16)a.w;
            v[4] = (f16)b2.x; v[5] = (f16)b2.y; v[6] = (f16)b2.z; v[7] = (f16)b2.w;
            *(f16x8*)(wpT + (size_t)c * 8) = v;
        }
        return;
    }
    // ---- groupnorm branch ----
    int g = bidx & 31, b = bidx >> 5;
    const f32x4* x4 = (const f32x4*)(x + ((size_t)(b * GROUPS + g)) * (GSZ * NPIX));
    float s = 0.f, ss = 0.f;
    for (int i = threadIdx.x; i < GSZ * NPIX / 4; i += 256) {
        f32x4 v = x4[i];
        *(f32x4*)&xs[i * 4] = v;
        s  += v.x + v.y + v.z + v.w;
        ss += v.x * v.x + v.y * v.y + v.z * v.z + v.w * v.w;
    }
    for (int off = 32; off; off >>= 1) { s += __shfl_down(s, off); ss += __shfl_down(ss, off); }
    int wv = threadIdx.x >> 6, ln = threadIdx.x & 63;
    if (ln == 0) { red[wv] = s; red[4 + wv] = ss; }
    __syncthreads();
    if (threadIdx.x == 0) {
        float S = red[0] + red[1] + red[2] + red[3];
        float SS = red[4] + red[5] + red[6] + red[7];
        float mu = S / (GSZ * NPIX);
        float var = SS / (GSZ * NPIX) - mu * mu;
        stat2[0] = mu; stat2[1] = rsqrtf(var + EPS);
    }
    __syncthreads();
    float mu = stat2[0], rstd = stat2[1];
    int ch = threadIdx.x >> 7;
    int n  = threadIdx.x & 127;
    float gl[8], bl[8];
#pragma unroll
    for (int i = 0; i < 8; i++) {
        float gv = gamma[g * 16 + ch * 8 + i] * rstd;
        gl[i] = gv;
        bl[i] = beta[g * 16 + ch * 8 + i] - mu * gv;
    }
    f16* tb0 = xnT + ((size_t)(b * 8)) * 65536 + (g * 2 + ch) * 1024 + n * 8;
#pragma unroll
    for (int nt = 0; nt < 8; nt++) {
        f16x8 o;
#pragma unroll
        for (int i = 0; i < 8; i++)
            o[i] = (f16)(xs[(ch * 8 + i) * 1024 + nt * 128 + n] * gl[i] + bl[i]);
        *(f16x8*)(tb0 + (size_t)nt * 65536) = o;
    }
}

// ---------------- K2: QKV GEMM v1 (R10-measured), BK=64, gld16, 3 blocks/CU ----------------
__global__ __launch_bounds__(256, 3) void k_qkv(const f16* __restrict__ wT, const float* __restrict__ bias,
                                                const f16* __restrict__ xnT, f16* __restrict__ qF,
                                                f16* __restrict__ kTl, f16* __restrict__ vTl) {
    int nt = blockIdx.x, ot = blockIdx.y, b = blockIdx.z;
    int o0 = ot * 128;
    __shared__ union SM {
        struct { f16 As[8192]; f16 Bs[8192]; } s;
        f16 Cf[16384];
    } sm;
    __shared__ float biasS[128];
    if (threadIdx.x < 128) biasS[threadIdx.x] = bias[o0 + threadIdx.x];
    int tid = threadIdx.x, lane = tid & 63, wv = tid >> 6;
    int wr = wv >> 1, wc = wv & 1;
    int l15 = lane & 15, quad = lane >> 4;
    const f16* wA = wT + (size_t)ot * 65536;
    const f16* xB = xnT + ((size_t)(b * 8 + nt)) * 65536;
    f32x4 acc[4][4] = {};
    for (int kk = 0; kk < CH; kk += 64) {
        __syncthreads();
        const f16* sa = wA + (size_t)(kk >> 3) * 1024;
        const f16* sb = xB + (size_t)(kk >> 3) * 1024;
#pragma unroll
        for (int i = 0; i < 4; i++) {
            int s = wv * 4 + i;
            gld16(sa + (size_t)(s * 64 + lane) * 8, sm.s.As + s * 512);
            gld16(sb + (size_t)(s * 64 + lane) * 8, sm.s.Bs + s * 512);
        }
        __syncthreads();
#pragma unroll
        for (int dk = 0; dk < 2; dk++) {
            f16x8 af[4], bf[4];
#pragma unroll
            for (int t = 0; t < 4; t++) {
                af[t] = *(const f16x8*)(sm.s.As + (dk * 4 + quad) * 1024 + (wr * 64 + t * 16 + l15) * 8);
                bf[t] = *(const f16x8*)(sm.s.Bs + (dk * 4 + quad) * 1024 + (wc * 64 + t * 16 + l15) * 8);
            }
#pragma unroll
            for (int tm = 0; tm < 4; tm++)
#pragma unroll
                for (int tn = 0; tn < 4; tn++)
                    acc[tm][tn] = __builtin_amdgcn_mfma_f32_16x16x32_f16(af[tm], bf[tn], acc[tm][tn], 0, 0, 0);
        }
    }
    __syncthreads();
    int which = ot >> 2, h = ot & 3;
#pragma unroll
    for (int tm = 0; tm < 4; tm++)
#pragma unroll
        for (int tn = 0; tn < 4; tn++) {
            int ob = wr * 64 + tm * 16 + quad * 4;
            int n  = wc * 64 + tn * 16 + l15;
            f16x4 pv;
#pragma unroll
            for (int r = 0; r < 4; r++) pv[r] = (f16)(acc[tm][tn][r] + biasS[ob + r]);
            if (which == 0) {
                int addr = ((((n >> 5) * 2 + ((n >> 4) & 1)) * 4 + (ob >> 5)) * 512)
                         + ((ob >> 3) & 3) * 128 + (n & 15) * 8 + (quad & 1) * 4;
                *(f16x4*)&sm.Cf[addr] = pv;
            } else if (which == 1) {
                int addr = (ob >> 3) * 1024 + n * 8 + (quad & 1) * 4;
                *(f16x4*)&sm.Cf[addr] = pv;
            } else {
#pragma unroll
                for (int r = 0; r < 4; r++)
                    sm.Cf[(n >> 3) * 1024 + (ob + r) * 8 + (n & 7)] = pv[r];
            }
        }
    __syncthreads();
    f16* tb = (which == 0) ? (qF + ((size_t)((b * 4 + h) * 8 + nt)) * 16384)
            : (which == 1) ? (kTl + ((size_t)((b * 4 + h) * 8 + nt)) * 16384)
                           : (vTl + ((size_t)((b * 4 + h) * 8 + nt)) * 16384);
#pragma unroll
    for (int i = 0; i < 8; i++) {
        int cid = tid + i * 256;
        *(f16x8*)(tb + (size_t)cid * 8) = *(const f16x8*)(sm.Cf + cid * 8);
    }
}

// ---------------- K3: flash attention v6.1 (exact R7-measured version, FROZEN) ----------------
// __expf softmax, prefetch after P-store — this exact instruction mix measured
// 55 us / WRITE 22.5 MB; exp2f variants (R8/R9) triggered scheduler-induced spill.
__global__ __launch_bounds__(512, 1) void k_attn(const f16* __restrict__ qF, const f16* __restrict__ kTl,
                                                 const f16* __restrict__ vTl, f16* __restrict__ oT) {
    int bid = blockIdx.x;
    int ntp = bid >> 6, group = bid & 63;
    int b = group >> 2, h = group & 3;
    extern __shared__ f16 smem[];
    f16* Kl = smem;
    f16* Vl = smem + 16384;
    f16* PA = smem + 32768;
    f16* PB = smem + 49152;
    int tid = threadIdx.x, lane = tid & 63, wv = tid >> 6;
    int wq = wv & 3;
    int tile = wv >> 2;
    int nt = ntp * 2 + tile;
    int l15 = lane & 15, quad = lane >> 4;
    const f16* qb = qF + ((size_t)(group * 8 + nt)) * 16384;
    const f16* kb = kTl + (size_t)group * 8 * 16384;
    const f16* vb = vTl + (size_t)group * 8 * 16384;
    f16* Preg = tile ? PB : PA;

    f16x8 aq[2][4];
#pragma unroll
    for (int t = 0; t < 2; t++)
#pragma unroll
        for (int dk = 0; dk < 4; dk++) {
            int seg = (wq * 2 + t) * 4 + dk;
            f16x8 v = *(const f16x8*)(qb + seg * 512 + lane * 8);
            aq[t][dk] = v * (f16)0.08838834764831845f;
        }

    float m_i[2] = {-1e30f, -1e30f}, l_i[2] = {0.f, 0.f};
    f32x4 oaccT[2][8] = {};

    const f16* sbase = tile ? vb : kb;
    f16* dstL = tile ? Vl : Kl;
    f16x8 buf[8];
#pragma unroll
    for (int i = 0; i < 8; i++)
        buf[i] = *(const f16x8*)(sbase + (size_t)((wq * 8 + i) * 64 + lane) * 8);

    for (int mc = 0; mc < 8; mc++) {
        __syncthreads();
#pragma unroll
        for (int i = 0; i < 8; i++)
            *(f16x8*)&dstL[(wq * 8 + i) * 512 + lane * 8] = buf[i];
        __syncthreads();

        // S^T = K Q^T
        f32x4 st[2][8] = {};
#pragma unroll
        for (int dk = 0; dk < 4; dk++) {
            f16x8 kf[8];
#pragma unroll
            for (int t = 0; t < 8; t++)
                kf[t] = *(const f16x8*)&Kl[(dk * 4 + quad) * 1024 + (t * 16 + l15) * 8];
#pragma unroll
            for (int tr = 0; tr < 2; tr++)
#pragma unroll
                for (int tc = 0; tc < 8; tc++)
                    st[tr][tc] = __builtin_amdgcn_mfma_f32_16x16x32_f16(kf[tc], aq[tr][dk], st[tr][tc], 0, 0, 0);
        }

        // online softmax: pairwise-tree in-lane reductions + 2 shuffles
#pragma unroll
        for (int tr = 0; tr < 2; tr++) {
            float a[8];
#pragma unroll
            for (int tc = 0; tc < 8; tc++)
                a[tc] = fmaxf(fmaxf(st[tr][tc][0], st[tr][tc][1]), fmaxf(st[tr][tc][2], st[tr][tc][3]));
#pragma unroll
            for (int s = 4; s; s >>= 1)
#pragma unroll
                for (int k = 0; k < 4; k++) if (k < s) a[k] = fmaxf(a[k], a[k + s]);
            float mx = a[0];
            mx = fmaxf(mx, __shfl_xor(mx, 16));
            mx = fmaxf(mx, __shfl_xor(mx, 32));
            float mnew = fmaxf(m_i[tr], mx);
            float alpha = __expf(m_i[tr] - mnew);
            m_i[tr] = mnew;
            float r4[8];
#pragma unroll
            for (int tc = 0; tc < 8; tc++) {
                float p0 = __expf(st[tr][tc][0] - mnew);
                float p1 = __expf(st[tr][tc][1] - mnew);
                float p2 = __expf(st[tr][tc][2] - mnew);
                float p3 = __expf(st[tr][tc][3] - mnew);
                st[tr][tc][0] = p0; st[tr][tc][1] = p1;
                st[tr][tc][2] = p2; st[tr][tc][3] = p3;
                r4[tc] = (p0 + p1) + (p2 + p3);
            }
#pragma unroll
            for (int s = 4; s; s >>= 1)
#pragma unroll
                for (int k = 0; k < 4; k++) if (k < s) r4[k] += r4[k + s];
            float rs = r4[0];
            rs += __shfl_xor(rs, 16);
            rs += __shfl_xor(rs, 32);
            l_i[tr] = l_i[tr] * alpha + rs;
#pragma unroll
            for (int tc = 0; tc < 8; tc++) {
                oaccT[tr][tc].x *= alpha; oaccT[tr][tc].y *= alpha;
                oaccT[tr][tc].z *= alpha; oaccT[tr][tc].w *= alpha;
            }
        }

        // P store (wave-private rows)
#pragma unroll
        for (int tr = 0; tr < 2; tr++) {
            int n = wq * 32 + tr * 16 + l15;
#pragma unroll
            for (int tc = 0; tc < 8; tc++) {
                int blk = tc * 2 + (quad >> 1);
                f16x4 pv;
#pragma unroll
                for (int r = 0; r < 4; r++) pv[r] = (f16)st[tr][tc][r];
                *(f16x4*)&Preg[n * 128 + ((blk ^ (n & 15)) << 3) + ((quad & 1) << 2)] = pv;
            }
        }

        // prefetch next K or V tile
        if (mc < 7) {
            const f16* s = sbase + (size_t)(mc + 1) * 16384;
#pragma unroll
            for (int i = 0; i < 8; i++)
                buf[i] = *(const f16x8*)(s + (size_t)((wq * 8 + i) * 64 + lane) * 8);
        }

        // O^T += V^T P
#pragma unroll
        for (int mk = 0; mk < 4; mk++) {
            f16x8 vf[8], pf[2];
#pragma unroll
            for (int t = 0; t < 8; t++)
                vf[t] = *(const f16x8*)&Vl[(mk * 4 + quad) * 1024 + (t * 16 + l15) * 8];
#pragma unroll
            for (int tr = 0; tr < 2; tr++) {
                int n = wq * 32 + tr * 16 + l15;
                int blk = mk * 4 + quad;
                pf[tr] = *(const f16x8*)&Preg[n * 128 + ((blk ^ (n & 15)) << 3)];
            }
#pragma unroll
            for (int tr = 0; tr < 2; tr++)
#pragma unroll
                for (int tc = 0; tc < 8; tc++)
                    oaccT[tr][tc] = __builtin_amdgcn_mfma_f32_16x16x32_f16(vf[tc], pf[tr], oaccT[tr][tc], 0, 0, 0);
        }
    }

    // epilogue: O -> own P region, then block-coalesced f16x8 stores
#pragma unroll
    for (int tr = 0; tr < 2; tr++) {
        float inv = 1.f / l_i[tr];
        int n = wq * 32 + tr * 16 + l15;
#pragma unroll
        for (int tc = 0; tc < 8; tc++) {
            int blk = tc * 2 + (quad >> 1);
            f16x4 ov;
#pragma unroll
            for (int r = 0; r < 4; r++) ov[r] = (f16)(oaccT[tr][tc][r] * inv);
            *(f16x4*)&Preg[n * 128 + ((blk ^ (n & 15)) << 3) + ((quad & 1) << 2)] = ov;
        }
    }
    __syncthreads();
    f16* ob = oT + ((size_t)(b * 8 + nt)) * 65536;
    int t256 = tid & 255;
#pragma unroll
    for (int i = 0; i < 8; i++) {
        int cid = t256 + i * 256;
        int cbl = cid >> 7, n = cid & 127;
        f16x8 v = *(const f16x8*)&Preg[n * 128 + ((cbl ^ (n & 15)) << 3)];
        *(f16x8*)(ob + (size_t)(h * 16 + cbl) * 1024 + n * 8) = v;
    }
}

// ---------------- K4: proj GEMM + bias + residual -> fp32 out ----------------
__global__ __launch_bounds__(256, 3) void k_proj(const f16* __restrict__ wT, const float* __restrict__ bias,
                                                 const f16* __restrict__ oT, const float* __restrict__ x,
                                                 float* __restrict__ out) {
    int nt = blockIdx.x, ot = blockIdx.y, b = blockIdx.z;
    int n0 = nt * 128, o0 = ot * 128;
    __shared__ union SM {
        struct { f16 As[8192]; f16 Bs[8192]; } s;
        f16 Cs[128][136];
    } sm;
    __shared__ float biasS[128];
    if (threadIdx.x < 128) biasS[threadIdx.x] = bias[o0 + threadIdx.x];
    int tid = threadIdx.x, lane = tid & 63, wv = tid >> 6;
    int wr = wv >> 1, wc = wv & 1;
    int l15 = lane & 15, quad = lane >> 4;
    const f16* wA = wT + (size_t)ot * 65536;
    const f16* xB = oT + ((size_t)(b * 8 + nt)) * 65536;
    f32x4 acc[4][4] = {};
    for (int kk = 0; kk < CH; kk += 64) {
        __syncthreads();
        const f16* sa = wA + (size_t)(kk >> 3) * 1024;
        const f16* sb = xB + (size_t)(kk >> 3) * 1024;
#pragma unroll
        for (int i = 0; i < 4; i++) {
            int s = wv * 4 + i;
            gld16(sa + (size_t)(s * 64 + lane) * 8, sm.s.As + s * 512);
            gld16(sb + (size_t)(s * 64 + lane) * 8, sm.s.Bs + s * 512);
        }
        __syncthreads();
#pragma unroll
        for (int dk = 0; dk < 2; dk++) {
            f16x8 af[4], bf[4];
#pragma unroll
            for (int t = 0; t < 4; t++) {
                af[t] = *(const f16x8*)(sm.s.As + (dk * 4 + quad) * 1024 + (wr * 64 + t * 16 + l15) * 8);
                bf[t] = *(const f16x8*)(sm.s.Bs + (dk * 4 + quad) * 1024 + (wc * 64 + t * 16 + l15) * 8);
            }
#pragma unroll
            for (int tm = 0; tm < 4; tm++)
#pragma unroll
                for (int tn = 0; tn < 4; tn++)
                    acc[tm][tn] = __builtin_amdgcn_mfma_f32_16x16x32_f16(af[tm], bf[tn], acc[tm][tn], 0, 0, 0);
        }
    }
    __syncthreads();
#pragma unroll
    for (int tm = 0; tm < 4; tm++)
#pragma unroll
        for (int tn = 0; tn < 4; tn++)
#pragma unroll
            for (int r = 0; r < 4; r++) {
                int o = wr * 64 + tm * 16 + quad * 4 + r;
                int n = wc * 64 + tn * 16 + l15;
                sm.Cs[o][n] = (f16)(acc[tm][tn][r] + biasS[o]);
            }
    __syncthreads();
#pragma unroll
    for (int i = 0; i < 8; i++) {
        int cid = tid + i * 256;
        int row = cid >> 4, off = (cid & 15) * 8;
        f16x8 v = *(const f16x8*)&sm.Cs[row][off];
        size_t gofs = ((size_t)(b * CH) + o0 + row) * NPIX + n0 + off;
        const float* xp = x + gofs;
        float* op = out + gofs;
        f32x4 o0v, o1v;
        o0v.x = xp[0] + (float)v[0]; o0v.y = xp[1] + (float)v[1];
        o0v.z = xp[2] + (float)v[2]; o0v.w = xp[3] + (float)v[3];
        o1v.x = xp[4] + (float)v[4]; o1v.y = xp[5] + (float)v[5];
        o1v.z = xp[6] + (float)v[6]; o1v.w = xp[7] + (float)v[7];
        *(f32x4*)op = o0v; *(f32x4*)(op + 4) = o1v;
    }
}

extern "C" void kernel_launch(void* const* d_in, const int* in_sizes, int n_in,
                              void* d_out, int out_size, void* d_ws, size_t ws_size,
                              hipStream_t stream) {
    const float* x     = (const float*)d_in[0];
    const float* gamma = (const float*)d_in[1];
    const float* beta  = (const float*)d_in[2];
    const float* wqkv  = (const float*)d_in[3];
    const float* bqkv  = (const float*)d_in[4];
    const float* wproj = (const float*)d_in[5];
    const float* bproj = (const float*)d_in[6];
    float* out = (float*)d_out;

    char* p = (char*)d_ws;
    f16* wqT = (f16*)p;           p += (size_t)3 * CH * CH * 2;
    f16* wpT = (f16*)p;           p += (size_t)CH * CH * 2;
    f16* xnT = (f16*)p;           p += (size_t)BATCH * NPIX * CH * 2;
    f16* qF  = (f16*)p;           p += (size_t)BATCH * HEADS * NPIX * HD * 2;
    f16* kTl = (f16*)p;           p += (size_t)BATCH * HEADS * NPIX * HD * 2;
    f16* vTl = (f16*)p;           p += (size_t)BATCH * HEADS * NPIX * HD * 2;
    f16* oT  = (f16*)p;           p += (size_t)BATCH * NPIX * CH * 2;

    k_pre<<<dim3(896), 256, 0, stream>>>(x, gamma, beta, xnT, wqkv, wproj, wqT, wpT);
    k_qkv<<<dim3(8, 12, BATCH), 256, 0, stream>>>(wqT, bqkv, xnT, qF, kTl, vTl);

    hipFuncSetAttribute((const void*)k_attn, hipFuncAttributeMaxDynamicSharedMemorySize, 131072);
    k_attn<<<dim3(256), 512, 131072, stream>>>(qF, kTl, vTl, oT);

    k_proj<<<dim3(8, 4, BATCH), 256, 0, stream>>>(wpT, bproj, oT, x, out);
}